// Round 1
// baseline (758.641 us; speedup 1.0000x reference)
//
#include <hip/hip_runtime.h>
#include <math.h>

#define MAXA 8400
#define TPB 256

__device__ __forceinline__ float sigmoidf_(float x){
    return 1.0f / (1.0f + expf(-x));
}

__device__ __forceinline__ float bce_(float x, float t){
    // max(x,0) - x*t + log1p(exp(-|x|))
    return fmaxf(x, 0.0f) - x * t + log1pf(expf(-fabsf(x)));
}

// IoU between box a (cx,cy,w,h) and box b (cx,cy,w,h) — mirrors _pairwise_iou.
__device__ float iou_fn(float ax, float ay, float aw, float ah,
                        float bx, float by, float bw, float bh){
#pragma clang fp contract(off)
    float tlx = fmaxf(ax - aw * 0.5f, bx - bw * 0.5f);
    float tly = fmaxf(ay - ah * 0.5f, by - bh * 0.5f);
    float brx = fminf(ax + aw * 0.5f, bx + bw * 0.5f);
    float bry = fminf(ay + ah * 0.5f, by + bh * 0.5f);
    float area_a = aw * ah;
    float area_b = bw * bh;
    bool  en = (tlx < brx) && (tly < bry);
    float area_i = en ? (brx - tlx) * (bry - tly) : 0.0f;
    return area_i / (area_a + area_b - area_i + 1e-16f);
}

// Full cost(m, a). MUST be bitwise-identical between assign (selection) and
// finalize (argmin conflict resolution) — hence contract(off).
__device__ float cost_eval(const float* __restrict__ o, float S1,
                           float xcv, float ycv, float rad,
                           float gx, float gy, float gw, float gh, int gc,
                           bool valid, bool fgflag){
#pragma clang fp contract(off)
    if (!(valid && fgflag)) return 1e9f;   // BIG
    float raw = iou_fn(gx, gy, gw, gh, o[0], o[1], o[2], o[3]);
    bool inb = (xcv > gx - 0.5f * gw) && (gx + 0.5f * gw > xcv) &&
               (ycv > gy - 0.5f * gh) && (gy + 0.5f * gh > ycv);
    bool inc = (xcv > gx - rad) && (xcv < gx + rad) &&
               (ycv > gy - rad) && (ycv < gy + rad);
    bool in_both = inb && inc;
    float so = sigmoidf_(o[4]);
    float pt = sqrtf(sigmoidf_(o[5 + gc]) * so);
    float logp = fmaxf(logf(pt), -100.0f);
    float l1mp = fmaxf(log1pf(-pt), -100.0f);
    float cls_cost = -(logp + S1 - l1mp);
    return cls_cost + 3.0f * (-logf(raw + 1e-8f)) + (in_both ? 0.0f : 100000.0f);
}

// ---------------- kernel 1: per-anchor S1mp and fg flag ----------------
__global__ __launch_bounds__(TPB) void precompute_kernel(
    const float* __restrict__ outputs, const float* __restrict__ xs,
    const float* __restrict__ ys, const float* __restrict__ st,
    const float* __restrict__ labels, float* __restrict__ S1mp,
    unsigned char* __restrict__ fgbuf, int A, int M, int C, int B)
{
    int idx = blockIdx.x * TPB + threadIdx.x;
    if (idx >= B * A) return;
    int b = idx / A;
    int a = idx - b * A;
    const float* o = outputs + (size_t)idx * (C + 5);

    float so = sigmoidf_(o[4]);
    float s = 0.0f;
    for (int c = 0; c < C; c++){
        float p = sqrtf(sigmoidf_(o[5 + c]) * so);
        s += fmaxf(log1pf(-p), -100.0f);
    }
    S1mp[idx] = s;

    float xcv = (xs[a] + 0.5f) * st[a];
    float ycv = (ys[a] + 0.5f) * st[a];
    float rad = 2.5f * st[a];
    bool any = false;
    for (int m = 0; m < M && !any; m++){
        const float* lab = labels + ((size_t)b * M + m) * 5;
        float gx = lab[0], gy = lab[1], gw = lab[2], gh = lab[3], g4 = lab[4];
        if (!((gx + gy + gw + gh + g4) > 0.0f)) continue;   // valid
        bool inb = (xcv > gx - 0.5f * gw) && (gx + 0.5f * gw > xcv) &&
                   (ycv > gy - 0.5f * gh) && (gy + 0.5f * gh > ycv);
        bool inc = (xcv > gx - rad) && (xcv < gx + rad) &&
                   (ycv > gy - rad) && (ycv < gy + rad);
        any = inb || inc;
    }
    fgbuf[idx] = any ? 1 : 0;
}

__global__ void zero_acc_kernel(float* acc){
    if (threadIdx.x < 4) acc[threadIdx.x] = 0.0f;
}

// ---------------- kernel 2: per-GT SimOTA assignment ----------------
__global__ __launch_bounds__(TPB) void assign_kernel(
    const float* __restrict__ outputs, const float* __restrict__ xs,
    const float* __restrict__ ys, const float* __restrict__ st,
    const float* __restrict__ labels, const float* __restrict__ S1mp,
    const unsigned char* __restrict__ fgbuf, unsigned char* __restrict__ matching,
    int A, int M, int C, int B)
{
    int b = blockIdx.x / M;
    int m = blockIdx.x - b * M;
    int t = threadIdx.x;

    const float* lab = labels + ((size_t)b * M + m) * 5;
    float gx = lab[0], gy = lab[1], gw = lab[2], gh = lab[3], g4 = lab[4];
    int  gc = (int)g4;
    bool valid = (gx + gy + gw + gh + g4) > 0.0f;

    unsigned char* mrow = matching + ((size_t)b * M + m) * (size_t)A;
    for (int a = t; a < A; a += TPB) mrow[a] = 0;
    if (!valid) return;

    __shared__ float sbuf[MAXA];
    __shared__ float rval[TPB];
    __shared__ int   ridx[TPB];

    const float* outb = outputs + (size_t)b * A * (C + 5);
    const unsigned char* fgb = fgbuf + (size_t)b * A;

    // ---- phase 1: masked ious into LDS ----
    for (int a = t; a < A; a += TPB){
        float v = 0.0f;
        if (fgb[a]){
            const float* o = outb + (size_t)a * (C + 5);
            v = iou_fn(gx, gy, gw, gh, o[0], o[1], o[2], o[3]);
        }
        sbuf[a] = v;
    }
    __syncthreads();

    // ---- top-10 iou sum (descending extraction == lax.top_k order) ----
    float topsum = 0.0f;
    for (int k = 0; k < 10; k++){
        float bv = -2.0f; int bi = 0x7fffffff;
        for (int a = t; a < A; a += TPB){
            float v = sbuf[a];
            if (v > bv){ bv = v; bi = a; }
        }
        rval[t] = bv; ridx[t] = bi;
        __syncthreads();
        for (int sft = TPB / 2; sft > 0; sft >>= 1){
            if (t < sft){
                float v2 = rval[t + sft]; int i2 = ridx[t + sft];
                if (v2 > rval[t] || (v2 == rval[t] && i2 < ridx[t])){
                    rval[t] = v2; ridx[t] = i2;
                }
            }
            __syncthreads();
        }
        topsum += rval[0];
        if (t == 0) sbuf[ridx[0]] = -1.0f;   // exclude
        __syncthreads();
    }
    int dyn_k = (int)topsum;          // trunc toward zero, values >= 0
    if (dyn_k < 1) dyn_k = 1;

    // ---- phase 2: cost into LDS ----
    for (int a = t; a < A; a += TPB){
        const float* o = outb + (size_t)a * (C + 5);
        float xcv = (xs[a] + 0.5f) * st[a];
        float ycv = (ys[a] + 0.5f) * st[a];
        float rad = 2.5f * st[a];
        sbuf[a] = cost_eval(o, S1mp[(size_t)b * A + a], xcv, ycv, rad,
                            gx, gy, gw, gh, gc, true, fgb[a] != 0);
    }
    __syncthreads();

    // ---- select dyn_k smallest costs, stable (value, index) order ----
    for (int k = 0; k < dyn_k; k++){
        float bv = 4e9f; int bi = 0x7fffffff;
        for (int a = t; a < A; a += TPB){
            float v = sbuf[a];
            if (v < bv){ bv = v; bi = a; }   // ascending a keeps smallest idx on ties
        }
        rval[t] = bv; ridx[t] = bi;
        __syncthreads();
        for (int sft = TPB / 2; sft > 0; sft >>= 1){
            if (t < sft){
                float v2 = rval[t + sft]; int i2 = ridx[t + sft];
                if (v2 < rval[t] || (v2 == rval[t] && i2 < ridx[t])){
                    rval[t] = v2; ridx[t] = i2;
                }
            }
            __syncthreads();
        }
        float wv = rval[0]; int wi = ridx[0];
        if (wv >= 1e8f) break;               // only BIG left: masked by fg&valid anyway
        if (t == 0){ mrow[wi] = 1; sbuf[wi] = 2e9f; }
        __syncthreads();
    }
}

// ---------------- kernel 3: conflict resolution + loss ----------------
__global__ __launch_bounds__(TPB) void finalize_kernel(
    const float* __restrict__ outputs, const float* __restrict__ xs,
    const float* __restrict__ ys, const float* __restrict__ st,
    const float* __restrict__ labels, const float* __restrict__ S1mp,
    const unsigned char* __restrict__ fgbuf, const unsigned char* __restrict__ matching,
    float* __restrict__ acc, int A, int M, int C, int B)
{
    int idx = blockIdx.x * TPB + threadIdx.x;
    float s_iou = 0.0f, s_obj = 0.0f, s_cls = 0.0f, s_nfg = 0.0f;
    if (idx < B * A){
        int b = idx / A;
        int a = idx - b * A;
        const float* o = outputs + (size_t)idx * (C + 5);

        int amg = 0, first = -1;
        for (int m = 0; m < M; m++){
            if (matching[((size_t)b * M + m) * A + a]){
                amg++;
                if (first < 0) first = m;
            }
        }
        int mgt = first;
        if (amg > 1){
            // jnp.argmin(cost[:, a]) — first minimum; recompute with identical fn
            float xcv = (xs[a] + 0.5f) * st[a];
            float ycv = (ys[a] + 0.5f) * st[a];
            float rad = 2.5f * st[a];
            float S1 = S1mp[idx];
            bool fgflag = fgbuf[idx] != 0;
            float best = 1e30f; int bi = 0;
            for (int m = 0; m < M; m++){
                const float* lab = labels + ((size_t)b * M + m) * 5;
                float gx = lab[0], gy = lab[1], gw = lab[2], gh = lab[3], g4 = lab[4];
                bool valid = (gx + gy + gw + gh + g4) > 0.0f;
                float c = cost_eval(o, S1, xcv, ycv, rad,
                                    gx, gy, gw, gh, (int)g4, valid, fgflag);
                if (c < best){ best = c; bi = m; }
            }
            mgt = bi;
        }

        bool fgf = amg >= 1;
        s_obj = bce_(o[4], fgf ? 1.0f : 0.0f);
        if (fgf){
            const float* lab = labels + ((size_t)b * M + mgt) * 5;
            float gx = lab[0], gy = lab[1], gw = lab[2], gh = lab[3];
            int gc = (int)lab[4];
            float pious = iou_fn(gx, gy, gw, gh, o[0], o[1], o[2], o[3]);
            s_iou = 1.0f - pious * pious;
            s_nfg = 1.0f;
            float cl = 0.0f;
            for (int c = 0; c < C; c++){
                float tt = (c == gc) ? pious : 0.0f;
                cl += bce_(o[5 + c], tt);
            }
            s_cls = cl;
        }
    }
    // wave64 shuffle reduction, then one atomic per wave per scalar
    for (int off = 32; off > 0; off >>= 1){
        s_iou += __shfl_down(s_iou, off);
        s_obj += __shfl_down(s_obj, off);
        s_cls += __shfl_down(s_cls, off);
        s_nfg += __shfl_down(s_nfg, off);
    }
    if ((threadIdx.x & 63) == 0){
        atomicAdd(&acc[0], s_iou);
        atomicAdd(&acc[1], s_obj);
        atomicAdd(&acc[2], s_cls);
        atomicAdd(&acc[3], s_nfg);
    }
}

__global__ void combine_kernel(const float* __restrict__ acc, float* __restrict__ out){
    float nfg = fmaxf(acc[3], 1.0f);
    out[0] = (5.0f * acc[0] + acc[1] + acc[2]) / nfg;
}

extern "C" void kernel_launch(void* const* d_in, const int* in_sizes, int n_in,
                              void* d_out, int out_size, void* d_ws, size_t ws_size,
                              hipStream_t stream)
{
    const float* outputs = (const float*)d_in[0];
    const float* xs      = (const float*)d_in[1];
    const float* ys      = (const float*)d_in[2];
    const float* st      = (const float*)d_in[3];
    const float* labels  = (const float*)d_in[4];

    const int C = 80;                       // fixed benchmark
    int A = in_sizes[1];
    int B = in_sizes[0] / (A * (C + 5));
    int M = in_sizes[4] / (B * 5);

    // workspace carve-up (16B aligned)
    char* w = (char*)d_ws;
    float* S1mp = (float*)w;
    w += (((size_t)B * A * sizeof(float)) + 255) & ~(size_t)255;
    float* acc = (float*)w;
    w += 256;
    unsigned char* fgbuf = (unsigned char*)w;
    w += (((size_t)B * A) + 255) & ~(size_t)255;
    unsigned char* matching = (unsigned char*)w;
    // needs B*M*A more bytes (~13.4 MB total ws use)

    int BA = B * A;
    int nb = (BA + TPB - 1) / TPB;

    precompute_kernel<<<dim3(nb), dim3(TPB), 0, stream>>>(
        outputs, xs, ys, st, labels, S1mp, fgbuf, A, M, C, B);
    zero_acc_kernel<<<dim3(1), dim3(64), 0, stream>>>(acc);
    assign_kernel<<<dim3(B * M), dim3(TPB), 0, stream>>>(
        outputs, xs, ys, st, labels, S1mp, fgbuf, matching, A, M, C, B);
    finalize_kernel<<<dim3(nb), dim3(TPB), 0, stream>>>(
        outputs, xs, ys, st, labels, S1mp, fgbuf, matching, acc, A, M, C, B);
    combine_kernel<<<dim3(1), dim3(1), 0, stream>>>(acc, (float*)d_out);
}

// Round 2
// 750.834 us; speedup vs baseline: 1.0104x; 1.0104x over previous
//
#include <hip/hip_runtime.h>
#include <math.h>

#define TPB 256

__device__ __forceinline__ float sigmoidf_(float x){
    return 1.0f / (1.0f + expf(-x));
}

__device__ __forceinline__ float bce_(float x, float t){
    // max(x,0) - x*t + log1p(exp(-|x|))
    return fmaxf(x, 0.0f) - x * t + log1pf(expf(-fabsf(x)));
}

// IoU between box a (cx,cy,w,h) and box b (cx,cy,w,h) — mirrors _pairwise_iou.
__device__ float iou_fn(float ax, float ay, float aw, float ah,
                        float bx, float by, float bw, float bh){
#pragma clang fp contract(off)
    float tlx = fmaxf(ax - aw * 0.5f, bx - bw * 0.5f);
    float tly = fmaxf(ay - ah * 0.5f, by - bh * 0.5f);
    float brx = fminf(ax + aw * 0.5f, bx + bw * 0.5f);
    float bry = fminf(ay + ah * 0.5f, by + bh * 0.5f);
    float area_a = aw * ah;
    float area_b = bw * bh;
    bool  en = (tlx < brx) && (tly < bry);
    float area_i = en ? (brx - tlx) * (bry - tly) : 0.0f;
    return area_i / (area_a + area_b - area_i + 1e-16f);
}

// Full cost(m, a). MUST be bitwise-identical between assign (selection) and
// finalize (argmin conflict resolution) — hence contract(off) and shared code.
__device__ float cost_eval(float ox, float oy, float ow, float oh,
                           float clslogit, float so, float S1,
                           float xcv, float ycv, float rad,
                           float gx, float gy, float gw, float gh,
                           bool valid, bool fgflag){
#pragma clang fp contract(off)
    if (!(valid && fgflag)) return 1e9f;   // BIG
    float raw = iou_fn(gx, gy, gw, gh, ox, oy, ow, oh);
    bool inb = (xcv > gx - 0.5f * gw) && (gx + 0.5f * gw > xcv) &&
               (ycv > gy - 0.5f * gh) && (gy + 0.5f * gh > ycv);
    bool inc = (xcv > gx - rad) && (xcv < gx + rad) &&
               (ycv > gy - rad) && (ycv < gy + rad);
    bool in_both = inb && inc;
    float pt = sqrtf(sigmoidf_(clslogit) * so);
    float logp = fmaxf(logf(pt), -100.0f);
    float l1mp = fmaxf(log1pf(-pt), -100.0f);
    float cls_cost = -(logp + S1 - l1mp);
    return cls_cost + 3.0f * (-logf(raw + 1e-8f)) + (in_both ? 0.0f : 100000.0f);
}

// ---------------- kernel 0: init scratch ----------------
__global__ __launch_bounds__(TPB) void init_kernel(int* __restrict__ amg,
                                                   unsigned int* __restrict__ firstm,
                                                   float* __restrict__ acc, int n){
    int i = blockIdx.x * TPB + threadIdx.x;
    if (i < n){ amg[i] = 0; firstm[i] = 0xFFFFFFFFu; }
    if (i < 4) acc[i] = 0.0f;
}

// ---------------- kernel 1: per-anchor precompute + SoA transpose ----------------
__global__ __launch_bounds__(TPB) void precompute_kernel(
    const float* __restrict__ outputs, const float* __restrict__ xs,
    const float* __restrict__ ys, const float* __restrict__ st,
    const float* __restrict__ labels,
    float* __restrict__ S1mp, float* __restrict__ sobj, float* __restrict__ obj4,
    float* __restrict__ bce0,
    float* __restrict__ bbx, float* __restrict__ bby,
    float* __restrict__ bbw, float* __restrict__ bbh,
    unsigned char* __restrict__ fgbuf, int A, int M, int C, int B)
{
    int idx = blockIdx.x * TPB + threadIdx.x;
    if (idx >= B * A) return;
    int b = idx / A;
    int a = idx - b * A;
    const float* o = outputs + (size_t)idx * (C + 5);

    float ox = o[0], oy = o[1], ow = o[2], ohh = o[3], x4 = o[4];
    bbx[idx] = ox; bby[idx] = oy; bbw[idx] = ow; bbh[idx] = ohh;

    float so = sigmoidf_(x4);
    float s1 = 0.0f, b0 = 0.0f;
#pragma unroll 4
    for (int c = 0; c < C; c++){
        float xc = o[5 + c];
        float p = sqrtf(sigmoidf_(xc) * so);
        s1 += fmaxf(log1pf(-p), -100.0f);
        b0 += fmaxf(xc, 0.0f) + log1pf(expf(-fabsf(xc)));
    }
    S1mp[idx] = s1; sobj[idx] = so; obj4[idx] = x4; bce0[idx] = b0;

    float xcv = (xs[a] + 0.5f) * st[a];
    float ycv = (ys[a] + 0.5f) * st[a];
    float rad = 2.5f * st[a];
    bool any = false;
    for (int m = 0; m < M && !any; m++){
        const float* lab = labels + ((size_t)b * M + m) * 5;
        float gx = lab[0], gy = lab[1], gw = lab[2], gh = lab[3], g4 = lab[4];
        if (!((gx + gy + gw + gh + g4) > 0.0f)) continue;   // valid
        bool inb = (xcv > gx - 0.5f * gw) && (gx + 0.5f * gw > xcv) &&
                   (ycv > gy - 0.5f * gh) && (gy + 0.5f * gh > ycv);
        bool inc = (xcv > gx - rad) && (xcv < gx + rad) &&
                   (ycv > gy - rad) && (ycv < gy + rad);
        any = inb || inc;
    }
    fgbuf[idx] = any ? 1 : 0;
}

// ---------------- kernel 2: per-GT SimOTA assignment ----------------
// One block per (b, m). Fused single pass builds per-thread top-10 iou list and
// bottom-10 (cost, idx) list in registers; tournament extraction with 1
// barrier/round. Selections published via atomics (no matching matrix).
__global__ __launch_bounds__(TPB) void assign_kernel(
    const float* __restrict__ outputs, const float* __restrict__ xs,
    const float* __restrict__ ys, const float* __restrict__ st,
    const float* __restrict__ labels, const float* __restrict__ S1mp,
    const float* __restrict__ sobj,
    const float* __restrict__ bbx, const float* __restrict__ bby,
    const float* __restrict__ bbw, const float* __restrict__ bbh,
    const unsigned char* __restrict__ fgbuf,
    int* __restrict__ amg, unsigned int* __restrict__ firstm,
    int A, int M, int C, int B)
{
    int b = blockIdx.x / M;
    int m = blockIdx.x - b * M;
    int t = threadIdx.x;
    int lane = t & 63, wid = t >> 6;

    const float* lab = labels + ((size_t)b * M + m) * 5;
    float gx = lab[0], gy = lab[1], gw = lab[2], gh = lab[3], g4 = lab[4];
    int  gc = (int)g4;
    bool valid = (gx + gy + gw + gh + g4) > 0.0f;
    if (!valid) return;   // uniform for whole block

    const size_t base = (size_t)b * A;
    const float* outb = outputs + base * (C + 5);
    const unsigned char* fgb = fgbuf + base;

    // per-thread lists (all statically indexed -> registers)
    float tv[10];                 // top-10 ious, descending
    float cv[10]; int ci[10];     // bottom-10 costs (value, anchor), ascending
#pragma unroll
    for (int j = 0; j < 10; j++){ tv[j] = -2.0f; cv[j] = 4e9f; ci[j] = 0x7fffffff; }

    // ---- fused pass: masked iou + full cost per anchor ----
    for (int a = t; a < A; a += TPB){
        float x0 = bbx[base + a], y0 = bby[base + a];
        float w0 = bbw[base + a], h0 = bbh[base + a];
        bool fgflag = fgb[a] != 0;

        float v = 0.0f;
        if (fgflag) v = iou_fn(gx, gy, gw, gh, x0, y0, w0, h0);
        if (v > tv[9]){
            tv[9] = v;
#pragma unroll
            for (int j = 9; j > 0; j--){
                if (tv[j] > tv[j-1]){ float tm = tv[j]; tv[j] = tv[j-1]; tv[j-1] = tm; }
            }
        }

        float xcv = (xs[a] + 0.5f) * st[a];
        float ycv = (ys[a] + 0.5f) * st[a];
        float rad = 2.5f * st[a];
        float c = cost_eval(x0, y0, w0, h0, outb[(size_t)a * (C + 5) + 5 + gc],
                            sobj[base + a], S1mp[base + a],
                            xcv, ycv, rad, gx, gy, gw, gh, true, fgflag);
        if (c < cv[9] || (c == cv[9] && a < ci[9])){
            cv[9] = c; ci[9] = a;
#pragma unroll
            for (int j = 9; j > 0; j--){
                if (cv[j] < cv[j-1] || (cv[j] == cv[j-1] && ci[j] < ci[j-1])){
                    float tf = cv[j]; cv[j] = cv[j-1]; cv[j-1] = tf;
                    int  ti = ci[j]; ci[j] = ci[j-1]; ci[j-1] = ti;
                }
            }
        }
    }

    __shared__ float swv[2][4];
    __shared__ int   swi[2][4];

    // ---- top-10 iou sum, descending extraction (== lax.top_k order) ----
    float topsum = 0.0f;
    for (int k = 0; k < 10; k++){
        float v = tv[0];
        int who = t;
#pragma unroll
        for (int off = 32; off; off >>= 1){
            float v2 = __shfl_xor(v, off);
            int   w2 = __shfl_xor(who, off);
            if (v2 > v || (v2 == v && w2 < who)){ v = v2; who = w2; }
        }
        int slot = k & 1;
        if (lane == 0){ swv[slot][wid] = v; swi[slot][wid] = who; }
        __syncthreads();
        float gv = swv[slot][0]; int gwho = swi[slot][0];
#pragma unroll
        for (int w = 1; w < 4; w++){
            float v2 = swv[slot][w]; int w2 = swi[slot][w];
            if (v2 > gv || (v2 == gv && w2 < gwho)){ gv = v2; gwho = w2; }
        }
        topsum += gv;
        if (t == gwho){
#pragma unroll
            for (int j = 0; j < 9; j++) tv[j] = tv[j+1];
            tv[9] = -2.0f;
        }
    }
    int dyn_k = (int)topsum;            // trunc toward zero; 0 <= topsum <= 10
    if (dyn_k < 1) dyn_k = 1;
    if (dyn_k > 10) dyn_k = 10;

    __syncthreads();

    // ---- select dyn_k smallest costs, stable (value, index) order ----
    for (int k = 0; k < dyn_k; k++){
        float v = cv[0]; int ai = ci[0];
#pragma unroll
        for (int off = 32; off; off >>= 1){
            float v2 = __shfl_xor(v, off);
            int   a2 = __shfl_xor(ai, off);
            if (v2 < v || (v2 == v && a2 < ai)){ v = v2; ai = a2; }
        }
        int slot = k & 1;
        if (lane == 0){ swv[slot][wid] = v; swi[slot][wid] = ai; }
        __syncthreads();
        float gv = swv[slot][0]; int gai = swi[slot][0];
#pragma unroll
        for (int w = 1; w < 4; w++){
            float v2 = swv[slot][w]; int a2 = swi[slot][w];
            if (v2 < gv || (v2 == gv && a2 < gai)){ gv = v2; gai = a2; }
        }
        if (gv >= 1e8f) break;          // only BIG left (masked by fg&valid)
        if (cv[0] == gv && ci[0] == gai){   // unique winner thread
            atomicAdd(&amg[base + gai], 1);
            atomicMin(&firstm[base + gai], (unsigned)m);
#pragma unroll
            for (int j = 0; j < 9; j++){ cv[j] = cv[j+1]; ci[j] = ci[j+1]; }
            cv[9] = 4e9f; ci[9] = 0x7fffffff;
        }
    }
}

// ---------------- kernel 3: conflict resolution + loss ----------------
__global__ __launch_bounds__(TPB) void finalize_kernel(
    const float* __restrict__ outputs, const float* __restrict__ xs,
    const float* __restrict__ ys, const float* __restrict__ st,
    const float* __restrict__ labels, const float* __restrict__ S1mp,
    const float* __restrict__ sobj, const float* __restrict__ obj4,
    const float* __restrict__ bce0,
    const float* __restrict__ bbx, const float* __restrict__ bby,
    const float* __restrict__ bbw, const float* __restrict__ bbh,
    const unsigned char* __restrict__ fgbuf,
    const int* __restrict__ amg, const unsigned int* __restrict__ firstm,
    float* __restrict__ acc, int A, int M, int C, int B)
{
    int idx = blockIdx.x * TPB + threadIdx.x;
    float s_iou = 0.0f, s_obj = 0.0f, s_cls = 0.0f, s_nfg = 0.0f;
    if (idx < B * A){
        int b = idx / A;
        int a = idx - b * A;
        int cnt = amg[idx];
        bool fgf = cnt >= 1;
        s_obj = bce_(obj4[idx], fgf ? 1.0f : 0.0f);
        if (fgf){
            float x0 = bbx[idx], y0 = bby[idx], w0 = bbw[idx], h0 = bbh[idx];
            int mgt = (int)firstm[idx];
            if (cnt > 1){
                // jnp.argmin(cost[:, a]) — first minimum; identical cost fn
                float xcv = (xs[a] + 0.5f) * st[a];
                float ycv = (ys[a] + 0.5f) * st[a];
                float rad = 2.5f * st[a];
                float S1 = S1mp[idx], so = sobj[idx];
                const float* orow = outputs + (size_t)idx * (C + 5);
                float best = 1e30f; int bi = 0;
                for (int m = 0; m < M; m++){
                    const float* lab = labels + ((size_t)b * M + m) * 5;
                    float gx = lab[0], gy = lab[1], gw = lab[2], gh = lab[3], g4 = lab[4];
                    bool valid = (gx + gy + gw + gh + g4) > 0.0f;
                    float c = cost_eval(x0, y0, w0, h0, orow[5 + (int)g4], so, S1,
                                        xcv, ycv, rad, gx, gy, gw, gh, valid, true);
                    if (c < best){ best = c; bi = m; }
                }
                mgt = bi;
            }
            const float* lab = labels + ((size_t)b * M + mgt) * 5;
            float pious = iou_fn(lab[0], lab[1], lab[2], lab[3], x0, y0, w0, h0);
            s_iou = 1.0f - pious * pious;
            s_nfg = 1.0f;
            int gc = (int)lab[4];
            // sum_c bce(x_c, pious*onehot) = sum_c bce(x_c,0) - x_gc*pious
            s_cls = bce0[idx] - outputs[(size_t)idx * (C + 5) + 5 + gc] * pious;
        }
    }
    // wave64 shuffle reduction, one atomic per wave per scalar
    for (int off = 32; off > 0; off >>= 1){
        s_iou += __shfl_down(s_iou, off);
        s_obj += __shfl_down(s_obj, off);
        s_cls += __shfl_down(s_cls, off);
        s_nfg += __shfl_down(s_nfg, off);
    }
    if ((threadIdx.x & 63) == 0){
        atomicAdd(&acc[0], s_iou);
        atomicAdd(&acc[1], s_obj);
        atomicAdd(&acc[2], s_cls);
        atomicAdd(&acc[3], s_nfg);
    }
}

__global__ void combine_kernel(const float* __restrict__ acc, float* __restrict__ out){
    float nfg = fmaxf(acc[3], 1.0f);
    out[0] = (5.0f * acc[0] + acc[1] + acc[2]) / nfg;
}

extern "C" void kernel_launch(void* const* d_in, const int* in_sizes, int n_in,
                              void* d_out, int out_size, void* d_ws, size_t ws_size,
                              hipStream_t stream)
{
    const float* outputs = (const float*)d_in[0];
    const float* xs      = (const float*)d_in[1];
    const float* ys      = (const float*)d_in[2];
    const float* st      = (const float*)d_in[3];
    const float* labels  = (const float*)d_in[4];

    const int C = 80;                       // fixed benchmark
    int A = in_sizes[1];
    int B = in_sizes[0] / (A * (C + 5));
    int M = in_sizes[4] / (B * 5);
    int BA = B * A;

    // workspace carve-up (256B aligned), ~11 MB total
    char* w = (char*)d_ws;
    auto carve = [&](size_t bytes) -> char* {
        char* p = w;
        w += (bytes + 255) & ~(size_t)255;
        return p;
    };
    float* S1mp = (float*)carve((size_t)BA * 4);
    float* sobj = (float*)carve((size_t)BA * 4);
    float* obj4 = (float*)carve((size_t)BA * 4);
    float* bce0 = (float*)carve((size_t)BA * 4);
    float* bbx  = (float*)carve((size_t)BA * 4);
    float* bby  = (float*)carve((size_t)BA * 4);
    float* bbw  = (float*)carve((size_t)BA * 4);
    float* bbh  = (float*)carve((size_t)BA * 4);
    int*   amg  = (int*)carve((size_t)BA * 4);
    unsigned int* firstm = (unsigned int*)carve((size_t)BA * 4);
    unsigned char* fgbuf = (unsigned char*)carve((size_t)BA);
    float* acc  = (float*)carve(256);

    int nb = (BA + TPB - 1) / TPB;

    init_kernel<<<dim3(nb), dim3(TPB), 0, stream>>>(amg, firstm, acc, BA);
    precompute_kernel<<<dim3(nb), dim3(TPB), 0, stream>>>(
        outputs, xs, ys, st, labels, S1mp, sobj, obj4, bce0,
        bbx, bby, bbw, bbh, fgbuf, A, M, C, B);
    assign_kernel<<<dim3(B * M), dim3(TPB), 0, stream>>>(
        outputs, xs, ys, st, labels, S1mp, sobj, bbx, bby, bbw, bbh,
        fgbuf, amg, firstm, A, M, C, B);
    finalize_kernel<<<dim3(nb), dim3(TPB), 0, stream>>>(
        outputs, xs, ys, st, labels, S1mp, sobj, obj4, bce0,
        bbx, bby, bbw, bbh, fgbuf, amg, firstm, acc, A, M, C, B);
    combine_kernel<<<dim3(1), dim3(1), 0, stream>>>(acc, (float*)d_out);
}

// Round 3
// 548.988 us; speedup vs baseline: 1.3819x; 1.3677x over previous
//
#include <hip/hip_runtime.h>
#include <math.h>

#define TPB 256

__device__ __forceinline__ float sigmoidf_(float x){
    return 1.0f / (1.0f + expf(-x));
}

__device__ __forceinline__ float bce_(float x, float t){
    // max(x,0) - x*t + log1p(exp(-|x|))
    return fmaxf(x, 0.0f) - x * t + log1pf(expf(-fabsf(x)));
}

// IoU between box a (cx,cy,w,h) and box b (cx,cy,w,h) — mirrors _pairwise_iou.
__device__ float iou_fn(float ax, float ay, float aw, float ah,
                        float bx, float by, float bw, float bh){
#pragma clang fp contract(off)
    float tlx = fmaxf(ax - aw * 0.5f, bx - bw * 0.5f);
    float tly = fmaxf(ay - ah * 0.5f, by - bh * 0.5f);
    float brx = fminf(ax + aw * 0.5f, bx + bw * 0.5f);
    float bry = fminf(ay + ah * 0.5f, by + bh * 0.5f);
    float area_a = aw * ah;
    float area_b = bw * bh;
    bool  en = (tlx < brx) && (tly < bry);
    float area_i = en ? (brx - tlx) * (bry - tly) : 0.0f;
    return area_i / (area_a + area_b - area_i + 1e-16f);
}

// Full cost(m, a). MUST be bitwise-identical between assign (selection) and
// finalize (argmin conflict resolution) — hence contract(off) and shared code.
__device__ float cost_eval(float ox, float oy, float ow, float oh,
                           float clslogit, float so, float S1,
                           float xcv, float ycv, float rad,
                           float gx, float gy, float gw, float gh,
                           bool valid, bool fgflag){
#pragma clang fp contract(off)
    if (!(valid && fgflag)) return 1e9f;   // BIG
    float raw = iou_fn(gx, gy, gw, gh, ox, oy, ow, oh);
    bool inb = (xcv > gx - 0.5f * gw) && (gx + 0.5f * gw > xcv) &&
               (ycv > gy - 0.5f * gh) && (gy + 0.5f * gh > ycv);
    bool inc = (xcv > gx - rad) && (xcv < gx + rad) &&
               (ycv > gy - rad) && (ycv < gy + rad);
    bool in_both = inb && inc;
    float pt = sqrtf(sigmoidf_(clslogit) * so);
    float logp = fmaxf(logf(pt), -100.0f);
    float l1mp = fmaxf(log1pf(-pt), -100.0f);
    float cls_cost = -(logp + S1 - l1mp);
    return cls_cost + 3.0f * (-logf(raw + 1e-8f)) + (in_both ? 0.0f : 100000.0f);
}

// ---------------- kernel 1: per-anchor precompute + SoA transpose ----------------
__global__ __launch_bounds__(TPB) void precompute_kernel(
    const float* __restrict__ outputs, const float* __restrict__ xs,
    const float* __restrict__ ys, const float* __restrict__ st,
    const float* __restrict__ labels,
    float* __restrict__ S1mp, float* __restrict__ sobj, float* __restrict__ obj4,
    float* __restrict__ bce0,
    float* __restrict__ bbx, float* __restrict__ bby,
    float* __restrict__ bbw, float* __restrict__ bbh,
    unsigned char* __restrict__ fgbuf,
    int* __restrict__ amg, unsigned int* __restrict__ firstm,
    float* __restrict__ xca, float* __restrict__ yca, float* __restrict__ rada,
    int A, int M, int C, int B)
{
    int idx = blockIdx.x * TPB + threadIdx.x;
    if (idx < A){
        float s = st[idx];
        xca[idx]  = (xs[idx] + 0.5f) * s;
        yca[idx]  = (ys[idx] + 0.5f) * s;
        rada[idx] = 2.5f * s;
    }
    if (idx >= B * A) return;
    amg[idx] = 0; firstm[idx] = 0xFFFFFFFFu;

    int b = idx / A;
    int a = idx - b * A;
    const float* o = outputs + (size_t)idx * (C + 5);

    float ox = o[0], oy = o[1], ow = o[2], ohh = o[3], x4 = o[4];
    bbx[idx] = ox; bby[idx] = oy; bbw[idx] = ow; bbh[idx] = ohh;

    float so = sigmoidf_(x4);
    float s1 = 0.0f, b0 = 0.0f;
#pragma unroll 4
    for (int c = 0; c < C; c++){
        float xc = o[5 + c];
        float p = sqrtf(sigmoidf_(xc) * so);
        s1 += fmaxf(log1pf(-p), -100.0f);
        b0 += fmaxf(xc, 0.0f) + log1pf(expf(-fabsf(xc)));
    }
    S1mp[idx] = s1; sobj[idx] = so; obj4[idx] = x4; bce0[idx] = b0;

    float xcv = (xs[a] + 0.5f) * st[a];
    float ycv = (ys[a] + 0.5f) * st[a];
    float rad = 2.5f * st[a];
    bool any = false;
    for (int m = 0; m < M && !any; m++){
        const float* lab = labels + ((size_t)b * M + m) * 5;
        float gx = lab[0], gy = lab[1], gw = lab[2], gh = lab[3], g4 = lab[4];
        if (!((gx + gy + gw + gh + g4) > 0.0f)) continue;   // valid
        bool inb = (xcv > gx - 0.5f * gw) && (gx + 0.5f * gw > xcv) &&
                   (ycv > gy - 0.5f * gh) && (gy + 0.5f * gh > ycv);
        bool inc = (xcv > gx - rad) && (xcv < gx + rad) &&
                   (ycv > gy - rad) && (ycv < gy + rad);
        any = inb || inc;
    }
    fgbuf[idx] = any ? 1 : 0;
}

// ---------------- kernel 2: per-GT SimOTA assignment ----------------
// One block per (b, m). Fused single pass builds per-thread top-10 iou list and
// bottom-10 (cost, idx) list in registers; tournament extraction with 1
// barrier/round. Selections published via scattered atomics (no contention).
__global__ __launch_bounds__(TPB) void assign_kernel(
    const float* __restrict__ outputs,
    const float* __restrict__ xca, const float* __restrict__ yca,
    const float* __restrict__ rada,
    const float* __restrict__ labels, const float* __restrict__ S1mp,
    const float* __restrict__ sobj,
    const float* __restrict__ bbx, const float* __restrict__ bby,
    const float* __restrict__ bbw, const float* __restrict__ bbh,
    const unsigned char* __restrict__ fgbuf,
    int* __restrict__ amg, unsigned int* __restrict__ firstm,
    int A, int M, int C, int B)
{
    int b = blockIdx.x / M;
    int m = blockIdx.x - b * M;
    int t = threadIdx.x;
    int lane = t & 63, wid = t >> 6;

    const float* lab = labels + ((size_t)b * M + m) * 5;
    float gx = lab[0], gy = lab[1], gw = lab[2], gh = lab[3], g4 = lab[4];
    int  gc = (int)g4;
    bool valid = (gx + gy + gw + gh + g4) > 0.0f;
    if (!valid) return;   // uniform for whole block

    const size_t base = (size_t)b * A;
    const float* outb = outputs + base * (C + 5);
    const unsigned char* fgb = fgbuf + base;

    // per-thread lists (statically indexed -> registers)
    float tv[10];                 // top-10 ious, descending
    float cv[10]; int ci[10];     // bottom-10 costs (value, anchor), ascending
#pragma unroll
    for (int j = 0; j < 10; j++){ tv[j] = -2.0f; cv[j] = 4e9f; ci[j] = 0x7fffffff; }

    // ---- fused pass: masked iou + full cost per anchor ----
    for (int a = t; a < A; a += TPB){
        float x0 = bbx[base + a], y0 = bby[base + a];
        float w0 = bbw[base + a], h0 = bbh[base + a];
        bool fgflag = fgb[a] != 0;

        float v = 0.0f;
        if (fgflag) v = iou_fn(gx, gy, gw, gh, x0, y0, w0, h0);
        if (v > tv[9]){
            tv[9] = v;
#pragma unroll
            for (int j = 9; j > 0; j--){
                if (tv[j] > tv[j-1]){ float tm = tv[j]; tv[j] = tv[j-1]; tv[j-1] = tm; }
            }
        }

        float c = cost_eval(x0, y0, w0, h0, outb[(size_t)a * (C + 5) + 5 + gc],
                            sobj[base + a], S1mp[base + a],
                            xca[a], yca[a], rada[a], gx, gy, gw, gh, true, fgflag);
        if (c < cv[9] || (c == cv[9] && a < ci[9])){
            cv[9] = c; ci[9] = a;
#pragma unroll
            for (int j = 9; j > 0; j--){
                if (cv[j] < cv[j-1] || (cv[j] == cv[j-1] && ci[j] < ci[j-1])){
                    float tf = cv[j]; cv[j] = cv[j-1]; cv[j-1] = tf;
                    int  ti = ci[j]; ci[j] = ci[j-1]; ci[j-1] = ti;
                }
            }
        }
    }

    __shared__ float swv[2][4];
    __shared__ int   swi[2][4];

    // ---- top-10 iou sum, descending extraction (== lax.top_k order) ----
    float topsum = 0.0f;
    for (int k = 0; k < 10; k++){
        float v = tv[0];
        int who = t;
#pragma unroll
        for (int off = 32; off; off >>= 1){
            float v2 = __shfl_xor(v, off);
            int   w2 = __shfl_xor(who, off);
            if (v2 > v || (v2 == v && w2 < who)){ v = v2; who = w2; }
        }
        int slot = k & 1;
        if (lane == 0){ swv[slot][wid] = v; swi[slot][wid] = who; }
        __syncthreads();
        float gv = swv[slot][0]; int gwho = swi[slot][0];
#pragma unroll
        for (int w = 1; w < 4; w++){
            float v2 = swv[slot][w]; int w2 = swi[slot][w];
            if (v2 > gv || (v2 == gv && w2 < gwho)){ gv = v2; gwho = w2; }
        }
        topsum += gv;
        if (t == gwho){
#pragma unroll
            for (int j = 0; j < 9; j++) tv[j] = tv[j+1];
            tv[9] = -2.0f;
        }
    }
    int dyn_k = (int)topsum;            // trunc toward zero; 0 <= topsum <= 10
    if (dyn_k < 1) dyn_k = 1;
    if (dyn_k > 10) dyn_k = 10;

    __syncthreads();

    // ---- select dyn_k smallest costs, stable (value, index) order ----
    for (int k = 0; k < dyn_k; k++){
        float v = cv[0]; int ai = ci[0];
#pragma unroll
        for (int off = 32; off; off >>= 1){
            float v2 = __shfl_xor(v, off);
            int   a2 = __shfl_xor(ai, off);
            if (v2 < v || (v2 == v && a2 < ai)){ v = v2; ai = a2; }
        }
        int slot = k & 1;
        if (lane == 0){ swv[slot][wid] = v; swi[slot][wid] = ai; }
        __syncthreads();
        float gv = swv[slot][0]; int gai = swi[slot][0];
#pragma unroll
        for (int w = 1; w < 4; w++){
            float v2 = swv[slot][w]; int a2 = swi[slot][w];
            if (v2 < gv || (v2 == gv && a2 < gai)){ gv = v2; gai = a2; }
        }
        if (gv >= 1e8f) break;          // only BIG left (masked by fg&valid)
        if (cv[0] == gv && ci[0] == gai){   // unique winner thread
            atomicAdd(&amg[base + gai], 1);
            atomicMin(&firstm[base + gai], (unsigned)m);
#pragma unroll
            for (int j = 0; j < 9; j++){ cv[j] = cv[j+1]; ci[j] = ci[j+1]; }
            cv[9] = 4e9f; ci[9] = 0x7fffffff;
        }
    }
}

// ---------------- kernel 3: conflict resolution + loss (block partials) ----------------
__global__ __launch_bounds__(TPB) void finalize_kernel(
    const float* __restrict__ outputs,
    const float* __restrict__ xca, const float* __restrict__ yca,
    const float* __restrict__ rada,
    const float* __restrict__ labels, const float* __restrict__ S1mp,
    const float* __restrict__ sobj, const float* __restrict__ obj4,
    const float* __restrict__ bce0,
    const float* __restrict__ bbx, const float* __restrict__ bby,
    const float* __restrict__ bbw, const float* __restrict__ bbh,
    const unsigned char* __restrict__ fgbuf,
    const int* __restrict__ amg, const unsigned int* __restrict__ firstm,
    float* __restrict__ pacc, int A, int M, int C, int B)
{
    int idx = blockIdx.x * TPB + threadIdx.x;
    float s_iou = 0.0f, s_obj = 0.0f, s_cls = 0.0f, s_nfg = 0.0f;
    if (idx < B * A){
        int b = idx / A;
        int a = idx - b * A;
        int cnt = amg[idx];
        bool fgf = cnt >= 1;
        s_obj = bce_(obj4[idx], fgf ? 1.0f : 0.0f);
        if (fgf){
            float x0 = bbx[idx], y0 = bby[idx], w0 = bbw[idx], h0 = bbh[idx];
            int mgt = (int)firstm[idx];
            if (cnt > 1){
                // jnp.argmin(cost[:, a]) — first minimum; identical cost fn
                float S1 = S1mp[idx], so = sobj[idx];
                const float* orow = outputs + (size_t)idx * (C + 5);
                float best = 1e30f; int bi = 0;
                for (int m = 0; m < M; m++){
                    const float* lab = labels + ((size_t)b * M + m) * 5;
                    float gx = lab[0], gy = lab[1], gw = lab[2], gh = lab[3], g4 = lab[4];
                    bool valid = (gx + gy + gw + gh + g4) > 0.0f;
                    float c = cost_eval(x0, y0, w0, h0, orow[5 + (int)g4], so, S1,
                                        xca[a], yca[a], rada[a],
                                        gx, gy, gw, gh, valid, true);
                    if (c < best){ best = c; bi = m; }
                }
                mgt = bi;
            }
            const float* lab = labels + ((size_t)b * M + mgt) * 5;
            float pious = iou_fn(lab[0], lab[1], lab[2], lab[3], x0, y0, w0, h0);
            s_iou = 1.0f - pious * pious;
            s_nfg = 1.0f;
            int gc = (int)lab[4];
            // sum_c bce(x_c, pious*onehot) = sum_c bce(x_c,0) - x_gc*pious
            s_cls = bce0[idx] - outputs[(size_t)idx * (C + 5) + 5 + gc] * pious;
        }
    }
    // wave64 shuffle reduction -> LDS -> one 4-float partial per block (NO atomics)
    for (int off = 32; off > 0; off >>= 1){
        s_iou += __shfl_down(s_iou, off);
        s_obj += __shfl_down(s_obj, off);
        s_cls += __shfl_down(s_cls, off);
        s_nfg += __shfl_down(s_nfg, off);
    }
    __shared__ float red[4][4];   // [wave][scalar]
    int lane = threadIdx.x & 63, wid = threadIdx.x >> 6;
    if (lane == 0){
        red[wid][0] = s_iou; red[wid][1] = s_obj;
        red[wid][2] = s_cls; red[wid][3] = s_nfg;
    }
    __syncthreads();
    if (threadIdx.x < 4){
        float v = red[0][threadIdx.x] + red[1][threadIdx.x]
                + red[2][threadIdx.x] + red[3][threadIdx.x];
        pacc[(size_t)blockIdx.x * 4 + threadIdx.x] = v;
    }
}

// ---------------- kernel 4: reduce block partials -> final loss ----------------
__global__ __launch_bounds__(TPB) void combine_kernel(
    const float* __restrict__ pacc, int nblk, float* __restrict__ out)
{
    float s0 = 0.0f, s1 = 0.0f, s2 = 0.0f, s3 = 0.0f;
    for (int i = threadIdx.x; i < nblk; i += TPB){
        s0 += pacc[(size_t)i * 4 + 0];
        s1 += pacc[(size_t)i * 4 + 1];
        s2 += pacc[(size_t)i * 4 + 2];
        s3 += pacc[(size_t)i * 4 + 3];
    }
    for (int off = 32; off > 0; off >>= 1){
        s0 += __shfl_down(s0, off);
        s1 += __shfl_down(s1, off);
        s2 += __shfl_down(s2, off);
        s3 += __shfl_down(s3, off);
    }
    __shared__ float red[4][4];
    int lane = threadIdx.x & 63, wid = threadIdx.x >> 6;
    if (lane == 0){ red[wid][0] = s0; red[wid][1] = s1; red[wid][2] = s2; red[wid][3] = s3; }
    __syncthreads();
    if (threadIdx.x == 0){
        float t0 = red[0][0] + red[1][0] + red[2][0] + red[3][0];
        float t1 = red[0][1] + red[1][1] + red[2][1] + red[3][1];
        float t2 = red[0][2] + red[1][2] + red[2][2] + red[3][2];
        float t3 = red[0][3] + red[1][3] + red[2][3] + red[3][3];
        float nfg = fmaxf(t3, 1.0f);
        out[0] = (5.0f * t0 + t1 + t2) / nfg;
    }
}

extern "C" void kernel_launch(void* const* d_in, const int* in_sizes, int n_in,
                              void* d_out, int out_size, void* d_ws, size_t ws_size,
                              hipStream_t stream)
{
    const float* outputs = (const float*)d_in[0];
    const float* xs      = (const float*)d_in[1];
    const float* ys      = (const float*)d_in[2];
    const float* st      = (const float*)d_in[3];
    const float* labels  = (const float*)d_in[4];

    const int C = 80;                       // fixed benchmark
    int A = in_sizes[1];
    int B = in_sizes[0] / (A * (C + 5));
    int M = in_sizes[4] / (B * 5);
    int BA = B * A;
    int nb = (BA + TPB - 1) / TPB;

    // workspace carve-up (256B aligned), ~11 MB total
    char* w = (char*)d_ws;
    auto carve = [&](size_t bytes) -> char* {
        char* p = w;
        w += (bytes + 255) & ~(size_t)255;
        return p;
    };
    float* S1mp = (float*)carve((size_t)BA * 4);
    float* sobj = (float*)carve((size_t)BA * 4);
    float* obj4 = (float*)carve((size_t)BA * 4);
    float* bce0 = (float*)carve((size_t)BA * 4);
    float* bbx  = (float*)carve((size_t)BA * 4);
    float* bby  = (float*)carve((size_t)BA * 4);
    float* bbw  = (float*)carve((size_t)BA * 4);
    float* bbh  = (float*)carve((size_t)BA * 4);
    int*   amg  = (int*)carve((size_t)BA * 4);
    unsigned int* firstm = (unsigned int*)carve((size_t)BA * 4);
    unsigned char* fgbuf = (unsigned char*)carve((size_t)BA);
    float* xca  = (float*)carve((size_t)A * 4);
    float* yca  = (float*)carve((size_t)A * 4);
    float* rada = (float*)carve((size_t)A * 4);
    float* pacc = (float*)carve((size_t)nb * 4 * 4);

    precompute_kernel<<<dim3(nb), dim3(TPB), 0, stream>>>(
        outputs, xs, ys, st, labels, S1mp, sobj, obj4, bce0,
        bbx, bby, bbw, bbh, fgbuf, amg, firstm, xca, yca, rada, A, M, C, B);
    assign_kernel<<<dim3(B * M), dim3(TPB), 0, stream>>>(
        outputs, xca, yca, rada, labels, S1mp, sobj, bbx, bby, bbw, bbh,
        fgbuf, amg, firstm, A, M, C, B);
    finalize_kernel<<<dim3(nb), dim3(TPB), 0, stream>>>(
        outputs, xca, yca, rada, labels, S1mp, sobj, obj4, bce0,
        bbx, bby, bbw, bbh, fgbuf, amg, firstm, pacc, A, M, C, B);
    combine_kernel<<<dim3(1), dim3(TPB), 0, stream>>>(pacc, nb, (float*)d_out);
}